// Round 3
// 190.534 us; speedup vs baseline: 1.0052x; 1.0052x over previous
//
#include <hip/hip_runtime.h>
#include <hip/hip_fp16.h>
#include <math.h>

// SGNS (skip-gram negative sampling) loss.  V=100000, D=128, N=262144, K=5.
//
// R7: guaranteed load pipelining via global_load_lds (fire-and-forget DMA to
// LDS, zero destination VGPRs). R5/R6 showed the allocator will NOT keep 14
// gather results live in VGPRs (VGPR=48 < 56 needed), serializing the gather
// (wave lifetime ~15k cy ~= 14 x 900cy misses back-to-back). The R6 asm-pin
// corrupted data (tied 128-bit asm operands) — dropped. Here each wave owns
// 4 pairs and issues 7 x 1KB global_load_lds (64 lanes x 16B; 4 rows per op,
// per-lane source addresses, wave-uniform LDS dest) with NO result registers,
// waits vmcnt(0) once, then each lane ds_read_b128's back exactly the 16B it
// fetched. 7KB LDS/wave, 28KB/block -> 5 blocks/CU, 20 waves/CU each with 7
// loads in flight. Wave-private LDS region -> no __syncthreads at all.
// Predict: VGPR ~32, LDS_Block_Size 28672, sgns 62 -> 35-45 us.

#define D 128
#define K 5

typedef _Float16 h2 __attribute__((ext_vector_type(2)));

__device__ __forceinline__ float log_sigmoid(float x) {
    // min(x,0) - log(1+exp(-|x|)); fast log/exp — abs err < 1e-6 here.
    return fminf(x, 0.0f) - __logf(1.0f + __expf(-fabsf(x)));
}

__device__ __forceinline__ float dot8_f16(uint4 a, uint4 b, float acc) {
    acc = __builtin_amdgcn_fdot2(__builtin_bit_cast(h2, a.x),
                                 __builtin_bit_cast(h2, b.x), acc, false);
    acc = __builtin_amdgcn_fdot2(__builtin_bit_cast(h2, a.y),
                                 __builtin_bit_cast(h2, b.y), acc, false);
    acc = __builtin_amdgcn_fdot2(__builtin_bit_cast(h2, a.z),
                                 __builtin_bit_cast(h2, b.z), acc, false);
    acc = __builtin_amdgcn_fdot2(__builtin_bit_cast(h2, a.w),
                                 __builtin_bit_cast(h2, b.w), acc, false);
    return acc;
}

// 16B global -> LDS direct (no VGPR destination). LDS dest is wave-uniform
// base; HW writes lane l's 16B at dest + l*16. Global src is per-lane.
__device__ __forceinline__ void gload16(const void* gptr, void* lptr) {
    __builtin_amdgcn_global_load_lds(
        (const __attribute__((address_space(1))) void*)gptr,
        (__attribute__((address_space(3))) void*)lptr,
        16, 0, 0);
}

// ---- fused fp32 -> fp16 conversion of both tables ------------------------
struct H8 { __half2 a, b, c, d; };

__global__ __launch_bounds__(256) void cvt2_f16_kernel(
    const float* __restrict__ src0, const float* __restrict__ src1,
    __half* __restrict__ dst0, __half* __restrict__ dst1, int n /*floats per table*/)
{
    int i = (blockIdx.x * blockDim.x + threadIdx.x) * 8;
    const float* src = src0;
    __half* dst = dst0;
    if (i >= n) { src = src1; dst = dst1; i -= n; }
    if (i >= n) return;
    float4 x = *(const float4*)(src + i);
    float4 y = *(const float4*)(src + i + 4);
    H8 h;
    h.a = __floats2half2_rn(x.x, x.y);
    h.b = __floats2half2_rn(x.z, x.w);
    h.c = __floats2half2_rn(y.x, y.y);
    h.d = __floats2half2_rn(y.z, y.w);
    *(H8*)(dst + i) = h;
}

// ---- fp16 gather via global_load_lds: 4 pairs/wave, 7 x 1KB ops ----------
__global__ __launch_bounds__(256) void sgns_f16_lds_kernel(
    const __half* __restrict__ embh,
    const __half* __restrict__ outh,
    const int* __restrict__ tgt_ids,
    const int* __restrict__ ctx_ids,
    const int* __restrict__ neg_ids,
    float* __restrict__ out,
    int N)
{
    // 4 waves/block x 7 ops x 1024B
    __shared__ alignas(16) char smem[4 * 7 * 1024];

    const int lane = threadIdx.x & 63;
    const int wave = threadIdx.x >> 6;
    const int lg   = lane & 15;        // 16B slot within a 256B row
    const int grp  = lane >> 4;        // which of the 4 rows in each 1KB op
    const int n_raw = (blockIdx.x * 4 + wave) * 4 + grp;
    const bool valid = n_raw < N;      // N % 16 == 0 -> always true; safety
    const int n = valid ? n_raw : N - 1;

    // ---- index loads (address chain) ----
    const int t = tgt_ids[n];
    int rows[K + 1];
    rows[0] = ctx_ids[n];
    {
        const int4 n4 = *(const int4*)(neg_ids + (size_t)n * K);
        rows[1] = n4.x; rows[2] = n4.y; rows[3] = n4.z; rows[4] = n4.w;
        rows[5] = neg_ids[(size_t)n * K + 4];
    }

    char* wbase = smem + wave * (7 * 1024);

    // ---- issue all 7 gathers, zero result VGPRs, all in flight ----
    gload16(embh + (size_t)t * D + lg * 8, wbase);               // op 0: input
#pragma unroll
    for (int j = 0; j < K + 1; ++j)
        gload16(outh + (size_t)rows[j] * D + lg * 8,             // ops 1..6
                wbase + (j + 1) * 1024);

    asm volatile("s_waitcnt vmcnt(0)" ::: "memory");
#if __has_builtin(__builtin_amdgcn_sched_barrier)
    __builtin_amdgcn_sched_barrier(0);
#endif

    // ---- each lane reads back exactly the 16B it fetched ----
    const char* myfrag = wbase + lane * 16;
    const uint4 in = *(const uint4*)(myfrag);
    float dot[K + 1];
#pragma unroll
    for (int j = 0; j < K + 1; ++j) {
        const uint4 w = *(const uint4*)(myfrag + (j + 1) * 1024);
        dot[j] = dot8_f16(in, w, 0.0f);
    }

    // ---- 16-lane butterfly reductions ----
#pragma unroll
    for (int j = 0; j < K + 1; ++j) {
        float v = dot[j];
        v += __shfl_xor(v, 1);
        v += __shfl_xor(v, 2);
        v += __shfl_xor(v, 4);
        v += __shfl_xor(v, 8);
        dot[j] = v;
    }

    if (lg == 0 && valid) {
        float loss = log_sigmoid(dot[0]);
#pragma unroll
        for (int j = 1; j < K + 1; ++j)
            loss += log_sigmoid(-dot[j]);
        out[n] = -loss;
    }
}

// ---- fp32 fallback if ws_size too small ----------------------------------
__global__ __launch_bounds__(256) void sgns_f32_kernel(
    const float* __restrict__ emb,
    const float* __restrict__ out_w,
    const int* __restrict__ tgt_ids,
    const int* __restrict__ ctx_ids,
    const int* __restrict__ neg_ids,
    float* __restrict__ out,
    int N)
{
    const int lane = threadIdx.x & 63;
    const int wave = threadIdx.x >> 6;
    const int lg   = lane & 15;
    const int grp  = lane >> 4;
    const int n = (blockIdx.x * 4 + wave) * 4 + grp;
    if (n >= N) return;

    const int t = tgt_ids[n];
    int rows[K + 1];
    rows[0] = ctx_ids[n];
    const int4 n4 = *(const int4*)(neg_ids + (size_t)n * K);
    rows[1] = n4.x; rows[2] = n4.y; rows[3] = n4.z; rows[4] = n4.w;
    rows[5] = neg_ids[(size_t)n * K + 4];

    const float4* er = (const float4*)(emb + (size_t)t * D);
    const float4 in0 = er[lg];
    const float4 in1 = er[lg + 16];

    float4 w0[K + 1], w1[K + 1];
#pragma unroll
    for (int j = 0; j < K + 1; ++j) {
        const float4* wr = (const float4*)(out_w + (size_t)rows[j] * D);
        w0[j] = wr[lg];
        w1[j] = wr[lg + 16];
    }

    float dot[K + 1];
#pragma unroll
    for (int j = 0; j < K + 1; ++j) {
        dot[j] = in0.x * w0[j].x + in0.y * w0[j].y
               + in0.z * w0[j].z + in0.w * w0[j].w
               + in1.x * w1[j].x + in1.y * w1[j].y
               + in1.z * w1[j].z + in1.w * w1[j].w;
    }

#pragma unroll
    for (int j = 0; j < K + 1; ++j) {
        float v = dot[j];
        v += __shfl_xor(v, 1);
        v += __shfl_xor(v, 2);
        v += __shfl_xor(v, 4);
        v += __shfl_xor(v, 8);
        dot[j] = v;
    }

    if (lg == 0) {
        float loss = log_sigmoid(dot[0]);
#pragma unroll
        for (int j = 1; j < K + 1; ++j)
            loss += log_sigmoid(-dot[j]);
        out[n] = -loss;
    }
}

extern "C" void kernel_launch(void* const* d_in, const int* in_sizes, int n_in,
                              void* d_out, int out_size, void* d_ws, size_t ws_size,
                              hipStream_t stream) {
    const float* emb     = (const float*)d_in[0];
    const float* out_w   = (const float*)d_in[1];
    const int*   tgt_ids = (const int*)d_in[2];
    const int*   ctx_ids = (const int*)d_in[3];
    const int*   neg_ids = (const int*)d_in[4];
    float* out = (float*)d_out;

    const int N = in_sizes[2];                 // 262144 pairs
    const size_t vd = (size_t)in_sizes[0];     // V*D floats per table
    const size_t need = 2 * vd * sizeof(__half);

    if (ws_size >= need) {
        __half* embh = (__half*)d_ws;
        __half* outh = embh + vd;
        const int cvt_threads = (int)(2 * vd / 8);
        const int cvt_blocks = (cvt_threads + 255) / 256;
        cvt2_f16_kernel<<<cvt_blocks, 256, 0, stream>>>(emb, out_w, embh, outh,
                                                        (int)vd);
        const int blocks = (N + 15) / 16;      // 16 pairs per 256-thread block
        sgns_f16_lds_kernel<<<blocks, 256, 0, stream>>>(embh, outh, tgt_ids,
                                                        ctx_ids, neg_ids, out, N);
    } else {
        const int blocks = (N + 15) / 16;
        sgns_f32_kernel<<<blocks, 256, 0, stream>>>(emb, out_w, tgt_ids,
                                                    ctx_ids, neg_ids, out, N);
    }
}